// Round 11
// baseline (405.132 us; speedup 1.0000x reference)
//
#include <hip/hip_runtime.h>
#include <hip/hip_bf16.h>
#include <math.h>

// Fused QKV(+bias) -> RoPE -> 4-head causal attention -> FC2(+bias) -> SiLU
// B=2048, L=119, D=128, H=4, HD=32. fp32 in/out, bf16 MFMA internally.
// Head split: model channel c = d*4 + h. Head merge: out channel c' = h*32 + d.
//
// Round 10: kill the exposed L2 operand latency. Evidence R5-R9: per-wave
// issue rate pinned ~15% at any occupancy; W fragments were streamed from L2
// at point of use (no prefetch distance possible at VGPR~90). Fix: stage W in
// LDS per head-group phase (48KB, fragment order, coalesced bulk copy), next
// phase's W staged in the shadow of the current attention phase; FC2 W staged
// during g=1 attention. QKV/FC2 nt-loops rolled (#pragma unroll 1, single
// accumulator) -- also halves code size. Attention = R9 verbatim (32x32,
// lane-local softmax), qs/ks stride 40->36 (18 words/row, gcd(18,32)=2, free).
// Layouts (m74/m101): 32x32 C/D: col=lane&31, row=(reg&3)+8*(reg>>2)+4*(lane>>5).
// A: row=lane&31, k=(lane>>5)*8+j. B: col=lane&31, same k.
// LDS: Wlds 49,152 + qs/ks 2x18,432 + vT 16,384 + tabL 30,940 = 133,340 B.

#define L_SEQ 119
#define D_MODEL 128
#define SCALE 0.17677669529663687f  // 1/sqrt(32)
#define NEGINF -1e30f

typedef __bf16 bf16x8 __attribute__((ext_vector_type(8)));
typedef __bf16 bf16x2 __attribute__((ext_vector_type(2)));
typedef float f32x4 __attribute__((ext_vector_type(4)));
typedef float f32x16 __attribute__((ext_vector_type(16)));

__global__ void rope_tab_kernel(unsigned* __restrict__ tabu) {
  int i = blockIdx.x * blockDim.x + threadIdx.x;
  if (i >= L_SEQ * 64) return;
  int l = i >> 6, j = i & 63;
  float inv = 1.0f / powf(10000.0f, (float)(2 * j) / 128.0f);
  float f = (float)l * inv;
  union { bf16x2 v; unsigned u; } cs;
  cs.v[0] = (__bf16)cosf(f);
  cs.v[1] = (__bf16)sinf(f);
  tabu[i] = cs.u;
}

// Wb: A-operand frags for QKV (A=W). flat = ((nt*8 + ks)*64 + lane)*8 + j
//   row chan d = lane&31 (tile nt = h*3+qkv), k = ks*16 + (lane>>5)*8 + j
//   source: Wqkv[(qkv*128 + d*4 + h)*128 + k]
__global__ void wprep_kernel(const float* __restrict__ Wqkv,
                             const float* __restrict__ bqkv,
                             __bf16* __restrict__ Wb, float* __restrict__ bb2) {
  int i = blockIdx.x * 256 + threadIdx.x;  // 0..49151
  int j = i & 7, lane = (i >> 3) & 63, ks = (i >> 9) & 7, nt = i >> 12;
  int d = lane & 31;
  int h = nt / 3, qkv = nt % 3;
  int k = ks * 16 + (lane >> 5) * 8 + j;
  Wb[i] = (__bf16)Wqkv[(qkv * 128 + d * 4 + h) * 128 + k];
  if (i < 384) {
    int nt2 = i >> 5, dd = i & 31;
    bb2[i] = bqkv[(nt2 % 3) * 128 + dd * 4 + (nt2 / 3)];
  }
}

// Wfc2 B-frags (16x16x32 path): flat = ((nt*4 + kb)*64 + lane)*8 + j
__global__ void wprep2_kernel(const float* __restrict__ Wfc2,
                              __bf16* __restrict__ Wf2b) {
  int i = blockIdx.x * 256 + threadIdx.x;  // 0..16383
  int j = i & 7, lane = (i >> 3) & 63, kb = (i >> 9) & 3, nt = i >> 11;
  int n = nt * 16 + (lane & 15);
  int k = kb * 32 + (lane >> 4) * 8 + j;
  Wf2b[i] = (__bf16)Wfc2[n * 128 + k];
}

__global__ __launch_bounds__(512) void fused_all(
    const float* __restrict__ x, const __bf16* __restrict__ Wb,
    const float* __restrict__ bb2, const unsigned* __restrict__ tabu,
    const __bf16* __restrict__ Wf2b, const float* __restrict__ bfc2,
    float* __restrict__ out) {
  __shared__ __align__(16) __bf16 Wlds[6 * 8 * 64 * 8];  // 49,152 B
  __shared__ __align__(16) __bf16 qs[2 * 128 * 36];      // 18,432 B
  __shared__ __align__(16) __bf16 ksm[2 * 128 * 36];     // 18,432 B
  __shared__ __align__(16) __bf16 vT[2 * 32 * 128];      // 16,384 B (XOR-swz)
  __shared__ unsigned tabL[L_SEQ * 65];                  // 30,940 B

  const int t = threadIdx.x, b = blockIdx.x;
  const int lane = t & 63, wv = t >> 6;
  const int ln31 = lane & 31, hi = lane >> 5;
  const int mt = wv & 3, ng = wv >> 2;  // QKV: M-tile, local-head group
  const int l_me = mt * 32 + ln31;
  const bool live = (l_me < L_SEQ);

  // ---- x A-fragments (once; reused by both g-phases)
  bf16x8 af[8];
  {
    int xr = live ? l_me : (L_SEQ - 1);
    const float* xrow = x + ((size_t)b * L_SEQ + xr) * 128;
#pragma unroll
    for (int ks = 0; ks < 8; ++ks) {
      float4 lo = *(const float4*)&xrow[ks * 16 + hi * 8];
      float4 hi4 = *(const float4*)&xrow[ks * 16 + hi * 8 + 4];
      bf16x8 v;
      v[0] = (__bf16)lo.x; v[1] = (__bf16)lo.y; v[2] = (__bf16)lo.z; v[3] = (__bf16)lo.w;
      v[4] = (__bf16)hi4.x; v[5] = (__bf16)hi4.y; v[6] = (__bf16)hi4.z; v[7] = (__bf16)hi4.w;
      af[ks] = v;
    }
  }
  // ---- stage RoPE table (stride 65 words), zero vT tail, stage W(g=0)
  for (int i = t; i < L_SEQ * 64; i += 512)
    tabL[(i >> 6) * 65 + (i & 63)] = tabu[i];
  for (int i = t; i < 2 * 32 * 9; i += 512) {
    int hd = i / 9, cc = L_SEQ + i % 9, d = hd & 31;
    vT[hd * 128 + (cc ^ ((d & 7) << 3))] = (__bf16)0.0f;
  }
  {
    const uint4* wsrc = (const uint4*)Wb;  // g=0 range
    uint4 w0 = wsrc[t], w1 = wsrc[512 + t], w2 = wsrc[1024 + t];
    uint4 w3 = wsrc[1536 + t], w4 = wsrc[2048 + t], w5 = wsrc[2560 + t];
    uint4* wd = (uint4*)Wlds;
    wd[t] = w0; wd[512 + t] = w1; wd[1024 + t] = w2;
    wd[1536 + t] = w3; wd[2048 + t] = w4; wd[2560 + t] = w5;
  }
  __syncthreads();

  for (int g = 0; g < 2; ++g) {
    // ======== QKV: rolled tt-loop (3 tiles/wave), W from LDS ========
#pragma unroll 1
    for (int tt = ng * 3; tt < ng * 3 + 3; ++tt) {
      f32x16 A = {};
#pragma unroll
      for (int ks = 0; ks < 8; ++ks) {
        bf16x8 wf = *(const bf16x8*)&Wlds[((tt * 8 + ks) * 64 + lane) * 8];
        A = __builtin_amdgcn_mfma_f32_32x32x16_bf16(wf, af[ks], A, 0, 0, 0);
      }
      const int hh2 = (tt >= 3) ? 1 : 0;
      const int qkv = tt - 3 * hh2;
      const int h = 2 * g + hh2;
      const int ntg = h * 3 + qkv;
      if (live) {
        if (qkv == 2) {  // v -> vT XOR-swizzled
#pragma unroll
          for (int rg = 0; rg < 16; ++rg) {
            const int d = (rg & 3) + 8 * (rg >> 2) + 4 * hi;
            float val = A[rg] + bb2[ntg * 32 + d];
            vT[(hh2 * 32 + d) * 128 + (l_me ^ ((d & 7) << 3))] = (__bf16)val;
          }
        } else {  // q or k: in-lane RoPE on reg pairs (rg, rg+8)
          __bf16* base = qkv ? ksm : qs;
#pragma unroll
          for (int rg = 0; rg < 8; ++rg) {
            const int c_lo = (rg & 3) + 8 * (rg >> 2);
            int d = c_lo + 4 * hi;  // 0..15
            union { bf16x2 v; unsigned u; } cs;
            cs.u = tabL[l_me * 65 + 4 * d + h];
            float c = (float)cs.v[0], s = (float)cs.v[1];
            float v1 = A[rg] + bb2[ntg * 32 + d];
            float v2 = A[rg + 8] + bb2[ntg * 32 + d + 16];
            if (qkv == 0) { v1 *= SCALE; v2 *= SCALE; }
            union { bf16x2 v; unsigned u; } pk;
            pk.v[0] = (__bf16)(v1 * c + v2 * s);
            pk.v[1] = (__bf16)(v2 * c - v1 * s);
            *(unsigned*)&base[(hh2 * 128 + l_me) * 36 + 2 * d] = pk.u;
          }
        }
      }
    }
    __syncthreads();  // epilogue done; Wlds free

    // ---- stage next-phase W into Wlds (shadowed by attention below)
    if (g == 0) {
      const uint4* wsrc = (const uint4*)(Wb + 24576);  // g=1 range
      uint4 w0 = wsrc[t], w1 = wsrc[512 + t], w2 = wsrc[1024 + t];
      uint4 w3 = wsrc[1536 + t], w4 = wsrc[2048 + t], w5 = wsrc[2560 + t];
      uint4* wd = (uint4*)Wlds;
      wd[t] = w0; wd[512 + t] = w1; wd[1024 + t] = w2;
      wd[1536 + t] = w3; wd[2048 + t] = w4; wd[2560 + t] = w5;
    } else {
      const uint4* wsrc = (const uint4*)Wf2b;  // 32KB
      uint4 w0 = wsrc[t], w1 = wsrc[512 + t], w2 = wsrc[1024 + t], w3 = wsrc[1536 + t];
      uint4* wd = (uint4*)Wlds;
      wd[t] = w0; wd[512 + t] = w1; wd[1024 + t] = w2; wd[1536 + t] = w3;
    }

    // ======== attention (R9-verbatim, stride 36): task (hh, qt) = (wv>>2, wv&3)
    {
      const int hh = wv >> 2, qt = wv & 3;
      const int h = 2 * g + hh;
      bf16x8 qf0 = *(const bf16x8*)&qs[(hh * 128 + qt * 32 + ln31) * 36 + hi * 8];
      bf16x8 qf1 = *(const bf16x8*)&qs[(hh * 128 + qt * 32 + ln31) * 36 + 16 + hi * 8];
      f32x16 s[4];
#pragma unroll
      for (int kt = 0; kt < 4; ++kt) {
        if (kt <= qt) {
          bf16x8 kf0 = *(const bf16x8*)&ksm[(hh * 128 + kt * 32 + ln31) * 36 + hi * 8];
          bf16x8 kf1 = *(const bf16x8*)&ksm[(hh * 128 + kt * 32 + ln31) * 36 + 16 + hi * 8];
          f32x16 z = {};
          z = __builtin_amdgcn_mfma_f32_32x32x16_bf16(kf0, qf0, z, 0, 0, 0);
          s[kt] = __builtin_amdgcn_mfma_f32_32x32x16_bf16(kf1, qf1, z, 0, 0, 0);
        }
      }
#pragma unroll
      for (int rg = 0; rg < 16; ++rg) {
        const int c_lo = (rg & 3) + 8 * (rg >> 2);
        int crow = c_lo + 4 * hi;
        s[qt][rg] = (crow <= ln31) ? s[qt][rg] : NEGINF;
      }
      float mx = NEGINF;
#pragma unroll
      for (int kt = 0; kt < 4; ++kt)
        if (kt <= qt)
#pragma unroll
          for (int rg = 0; rg < 16; ++rg) mx = fmaxf(mx, s[kt][rg]);
      mx = fmaxf(mx, __shfl_xor(mx, 32));
      float sum = 0.0f;
#pragma unroll
      for (int kt = 0; kt < 4; ++kt)
        if (kt <= qt)
#pragma unroll
          for (int rg = 0; rg < 16; ++rg) {
            s[kt][rg] = __expf(s[kt][rg] - mx);
            sum += s[kt][rg];
          }
      sum += __shfl_xor(sum, 32);
      float inv = 1.0f / sum;
      unsigned pk[4][8];
#pragma unroll
      for (int kt = 0; kt < 4; ++kt) {
        if (kt <= qt) {
#pragma unroll
          for (int p = 0; p < 8; ++p) {
            union { bf16x2 v; unsigned u; } w;
            w.v[0] = (__bf16)(s[kt][2 * p] * inv);
            w.v[1] = (__bf16)(s[kt][2 * p + 1] * inv);
            pk[kt][p] = w.u;
          }
        }
      }
      f32x16 o = {};
#pragma unroll
      for (int kt = 0; kt < 4; ++kt) {
        if (kt <= qt) {
#pragma unroll
          for (int m = 0; m < 2; ++m) {
            unsigned f0 = (unsigned)__shfl_xor((int)pk[kt][4 * m + 0], 32);
            unsigned f1 = (unsigned)__shfl_xor((int)pk[kt][4 * m + 1], 32);
            unsigned f2 = (unsigned)__shfl_xor((int)pk[kt][4 * m + 2], 32);
            unsigned f3 = (unsigned)__shfl_xor((int)pk[kt][4 * m + 3], 32);
            union { unsigned w[4]; bf16x8 v; } Aw;
            Aw.w[0] = hi ? f2 : pk[kt][4 * m + 0];
            Aw.w[1] = hi ? f3 : pk[kt][4 * m + 1];
            Aw.w[2] = hi ? pk[kt][4 * m + 2] : f0;
            Aw.w[3] = hi ? pk[kt][4 * m + 3] : f1;
            bf16x8 vf = *(const bf16x8*)&vT[(hh * 32 + ln31) * 128 +
                ((kt * 32 + m * 16 + hi * 8) ^ ((ln31 & 7) << 3))];
            o = __builtin_amdgcn_mfma_f32_32x32x16_bf16(Aw.v, vf, o, 0, 0, 0);
          }
        }
      }
#pragma unroll
      for (int rg = 0; rg < 16; ++rg) {
        const int c_lo = (rg & 3) + 8 * (rg >> 2);
        int l = qt * 32 + c_lo + 4 * hi;
        if (l < L_SEQ)
          out[((size_t)b * L_SEQ + l) * 128 + h * 32 + ln31] = o[rg];
      }
    }
    __syncthreads();  // attention done; next-phase W landed
  }

  // ======== FC2 + bias + SiLU: W from LDS, rolled nt-loop ========
  {
    const int ln15 = lane & 15, kg = lane >> 4;
    int yr = wv * 16 + ln15;
    if (yr > L_SEQ - 1) yr = L_SEQ - 1;
    const float* yrow = out + ((size_t)b * L_SEQ + yr) * 128;
    bf16x8 af2[4];
#pragma unroll
    for (int kb = 0; kb < 4; ++kb) {
      float4 lo = *(const float4*)&yrow[kb * 32 + kg * 8];
      float4 hi4 = *(const float4*)&yrow[kb * 32 + kg * 8 + 4];
      bf16x8 v;
      v[0] = (__bf16)lo.x; v[1] = (__bf16)lo.y; v[2] = (__bf16)lo.z; v[3] = (__bf16)lo.w;
      v[4] = (__bf16)hi4.x; v[5] = (__bf16)hi4.y; v[6] = (__bf16)hi4.z; v[7] = (__bf16)hi4.w;
      af2[kb] = v;
    }
#pragma unroll 1
    for (int nt = 0; nt < 8; ++nt) {
      f32x4 a2 = {};
#pragma unroll
      for (int kb = 0; kb < 4; ++kb)
        a2 = __builtin_amdgcn_mfma_f32_16x16x32_bf16(
            af2[kb], *(const bf16x8*)&Wlds[((nt * 4 + kb) * 64 + lane) * 8],
            a2, 0, 0, 0);
      float bc = bfc2[nt * 16 + ln15];
#pragma unroll
      for (int r = 0; r < 4; ++r) {
        int row = wv * 16 + kg * 4 + r, c = nt * 16 + ln15;
        if (row < L_SEQ) {
          float vv = a2[r] + bc;
          out[((size_t)b * L_SEQ + row) * 128 + c] = vv / (1.0f + __expf(-vv));
        }
      }
    }
  }
}

extern "C" void kernel_launch(void* const* d_in, const int* in_sizes, int n_in,
                              void* d_out, int out_size, void* d_ws,
                              size_t ws_size, hipStream_t stream) {
  const float* x = (const float*)d_in[0];
  const float* Wqkv = (const float*)d_in[1];
  const float* bqkv = (const float*)d_in[2];
  const float* Wfc2 = (const float*)d_in[3];
  const float* bfc2 = (const float*)d_in[4];
  float* out = (float*)d_out;

  char* ws = (char*)d_ws;
  unsigned* tabu = (unsigned*)ws;                        // 30,464 B (pad 30,720)
  __bf16* Wb = (__bf16*)(ws + 30720);                    // 98,304 B
  float* bb2 = (float*)(ws + 30720 + 98304);             //  1,536 B
  __bf16* Wf2b = (__bf16*)(ws + 30720 + 98304 + 1536);   // 32,768 B (end 163,328)

  const int B = in_sizes[0] / (L_SEQ * D_MODEL);  // 2048
  rope_tab_kernel<<<(L_SEQ * 64 + 255) / 256, 256, 0, stream>>>(tabu);
  wprep_kernel<<<192, 256, 0, stream>>>(Wqkv, bqkv, Wb, bb2);
  wprep2_kernel<<<64, 256, 0, stream>>>(Wfc2, Wf2b);
  fused_all<<<B, 512, 0, stream>>>(x, Wb, bb2, tabu, Wf2b, bfc2, out);
}

// Round 12
// 369.818 us; speedup vs baseline: 1.0955x; 1.0955x over previous
//
#include <hip/hip_runtime.h>
#include <hip/hip_bf16.h>
#include <math.h>

// Fused QKV(+bias) -> RoPE -> 4-head causal attention -> FC2(+bias) -> SiLU
// B=2048, L=119, D=128, H=4, HD=32. fp32 in/out, bf16 MFMA internally.
// Head split: model channel c = d*4 + h. Head merge: out channel c' = h*32 + d.
//
// Round 11: R9 base (best verified: 221.8us) + three clean cuts.
//  - y kept in LDS (bf16, XOR-swizzled both sides) instead of out->L2->back:
//    FC2 reads ds_read_b128; out written exactly once (WRITE=output only).
//    tabL dropped (tab read from L2, as R8 -- identical perf) to fund yL.
//  - qs/ks stride 40 -> 36 (18 words/row, 16 distinct bank slots; R10-verified
//    conflict cut 2.9M->1.7M).
//  - ALL large arrays phase-scoped (R10 lesson: af[8] hoisted across attention
//    -> 627MB scratch traffic; R9 discipline restored).
// Layouts (m74/m101): 32x32 C/D: col=lane&31, row=(reg&3)+8*(reg>>2)+4*(lane>>5).
// A: row=lane&31, k=(lane>>5)*8+j. B: col=lane&31, same k.
// LDS: qs/ksm [4][128][36] 2x36,864 + vT [4][32][128] 32,768 + yL [128][128]
// 32,768 = 139,264 B.

#define L_SEQ 119
#define D_MODEL 128
#define SCALE 0.17677669529663687f  // 1/sqrt(32)
#define NEGINF -1e30f

typedef __bf16 bf16x8 __attribute__((ext_vector_type(8)));
typedef __bf16 bf16x2 __attribute__((ext_vector_type(2)));
typedef float f32x4 __attribute__((ext_vector_type(4)));
typedef float f32x16 __attribute__((ext_vector_type(16)));

__global__ void rope_tab_kernel(unsigned* __restrict__ tabu) {
  int i = blockIdx.x * blockDim.x + threadIdx.x;
  if (i >= L_SEQ * 64) return;
  int l = i >> 6, j = i & 63;
  float inv = 1.0f / powf(10000.0f, (float)(2 * j) / 128.0f);
  float f = (float)l * inv;
  union { bf16x2 v; unsigned u; } cs;
  cs.v[0] = (__bf16)cosf(f);
  cs.v[1] = (__bf16)sinf(f);
  tabu[i] = cs.u;
}

// Wb: A-operand frags for QKV (A=W). flat = ((nt*8 + ks)*64 + lane)*8 + j
//   row chan d = lane&31 (tile nt = h*3+qkv), k = ks*16 + (lane>>5)*8 + j
//   source: Wqkv[(qkv*128 + d*4 + h)*128 + k]
__global__ void wprep_kernel(const float* __restrict__ Wqkv,
                             const float* __restrict__ bqkv,
                             __bf16* __restrict__ Wb, float* __restrict__ bb2) {
  int i = blockIdx.x * 256 + threadIdx.x;  // 0..49151
  int j = i & 7, lane = (i >> 3) & 63, ks = (i >> 9) & 7, nt = i >> 12;
  int d = lane & 31;
  int h = nt / 3, qkv = nt % 3;
  int k = ks * 16 + (lane >> 5) * 8 + j;
  Wb[i] = (__bf16)Wqkv[(qkv * 128 + d * 4 + h) * 128 + k];
  if (i < 384) {
    int nt2 = i >> 5, dd = i & 31;
    bb2[i] = bqkv[(nt2 % 3) * 128 + dd * 4 + (nt2 / 3)];
  }
}

// Wfc2 B-frags (16x16x32 path): flat = ((nt*4 + kb)*64 + lane)*8 + j
__global__ void wprep2_kernel(const float* __restrict__ Wfc2,
                              __bf16* __restrict__ Wf2b) {
  int i = blockIdx.x * 256 + threadIdx.x;  // 0..16383
  int j = i & 7, lane = (i >> 3) & 63, kb = (i >> 9) & 3, nt = i >> 11;
  int n = nt * 16 + (lane & 15);
  int k = kb * 32 + (lane >> 4) * 8 + j;
  Wf2b[i] = (__bf16)Wfc2[n * 128 + k];
}

__global__ __launch_bounds__(512) void fused_all(
    const float* __restrict__ x, const __bf16* __restrict__ Wb,
    const float* __restrict__ bb2, const unsigned* __restrict__ tabu,
    const __bf16* __restrict__ Wf2b, const float* __restrict__ bfc2,
    float* __restrict__ out) {
  __shared__ __align__(16) __bf16 qs[4 * 128 * 36];   // 36,864 B
  __shared__ __align__(16) __bf16 ksm[4 * 128 * 36];  // 36,864 B
  __shared__ __align__(16) __bf16 vT[4 * 32 * 128];   // 32,768 B (XOR-swz)
  __shared__ __align__(16) __bf16 yL[128 * 128];      // 32,768 B (XOR-swz)

  const int t = threadIdx.x, b = blockIdx.x;
  const int lane = t & 63, wv = t >> 6;
  const int ln31 = lane & 31, hi = lane >> 5;

  // ---- zero vT tail cols 119..127
  for (int i = t; i < 4 * 32 * 9; i += 512) {
    int hd = i / 9, cc = L_SEQ + i % 9, d = hd & 31;
    vT[hd * 128 + (cc ^ ((d & 7) << 3))] = (__bf16)0.0f;
  }

  // ======== QKV: wave -> Mtile (wv&3), Ntile-group (wv>>2)*6 .. +5 ========
  const int mt = wv & 3, g2 = wv >> 2;
  const int l_me = mt * 32 + ln31;  // this lane's sequence row (col of C)
  const bool live = (l_me < L_SEQ);
  {
    int xr = live ? l_me : (L_SEQ - 1);
    const float* xrow = x + ((size_t)b * L_SEQ + xr) * 128;
    bf16x8 af[8];
#pragma unroll
    for (int ks = 0; ks < 8; ++ks) {
      float4 lo = *(const float4*)&xrow[ks * 16 + hi * 8];
      float4 hi4 = *(const float4*)&xrow[ks * 16 + hi * 8 + 4];
      bf16x8 v;
      v[0] = (__bf16)lo.x; v[1] = (__bf16)lo.y; v[2] = (__bf16)lo.z; v[3] = (__bf16)lo.w;
      v[4] = (__bf16)hi4.x; v[5] = (__bf16)hi4.y; v[6] = (__bf16)hi4.z; v[7] = (__bf16)hi4.w;
      af[ks] = v;
    }
#pragma unroll
    for (int r = 0; r < 3; ++r) {
      const int nt0 = g2 * 6 + 2 * r, nt1 = nt0 + 1;
      f32x16 a0 = {}, a1 = {};
#pragma unroll
      for (int ks = 0; ks < 8; ++ks) {
        bf16x8 wf0 = *(const bf16x8*)&Wb[(((nt0 * 8 + ks) * 64) + lane) * 8];
        bf16x8 wf1 = *(const bf16x8*)&Wb[(((nt1 * 8 + ks) * 64) + lane) * 8];
        a0 = __builtin_amdgcn_mfma_f32_32x32x16_bf16(wf0, af[ks], a0, 0, 0, 0);
        a1 = __builtin_amdgcn_mfma_f32_32x32x16_bf16(wf1, af[ks], a1, 0, 0, 0);
      }
      // epilogues
#pragma unroll
      for (int e = 0; e < 2; ++e) {
        const int nt = e ? nt1 : nt0;
        const f32x16& A = e ? a1 : a0;
        const int h = nt / 3, qkv = nt % 3;
        if (qkv < 2) {  // q or k: RoPE in-lane on reg pairs (rg, rg+8)
          __bf16* base = (qkv == 0) ? qs : ksm;
          if (live) {
#pragma unroll
            for (int rg = 0; rg < 8; ++rg) {
              const int c_lo = (rg & 3) + 8 * (rg >> 2);
              int d = c_lo + 4 * hi;  // 0..15
              union { bf16x2 v; unsigned u; } cs;
              cs.u = tabu[l_me * 64 + 4 * d + h];
              float c = (float)cs.v[0], s = (float)cs.v[1];
              float v1 = A[rg] + bb2[nt * 32 + d];
              float v2 = A[rg + 8] + bb2[nt * 32 + d + 16];
              if (qkv == 0) { v1 *= SCALE; v2 *= SCALE; }
              union { bf16x2 v; unsigned u; } pk;
              pk.v[0] = (__bf16)(v1 * c + v2 * s);
              pk.v[1] = (__bf16)(v2 * c - v1 * s);
              *(unsigned*)&base[(h * 128 + l_me) * 36 + 2 * d] = pk.u;
            }
          }
        } else {  // v: write vT[h][d][l] XOR-swizzled
          if (live) {
#pragma unroll
            for (int rg = 0; rg < 16; ++rg) {
              const int d = (rg & 3) + 8 * (rg >> 2) + 4 * hi;  // 0..31
              float val = A[rg] + bb2[nt * 32 + d];
              vT[(h * 32 + d) * 128 + (l_me ^ ((d & 7) << 3))] = (__bf16)val;
            }
          }
        }
      }
    }
  }
  __syncthreads();

  // ======== attention: wave -> head (wv>>1); tasks qt = {wv&1, 3-(wv&1)} ====
  {
    const int h = wv >> 1;
#pragma unroll
    for (int ts = 0; ts < 2; ++ts) {
      const int qt = ts ? (3 - (wv & 1)) : (wv & 1);
      bf16x8 qf0 = *(const bf16x8*)&qs[(h * 128 + qt * 32 + ln31) * 36 + hi * 8];
      bf16x8 qf1 = *(const bf16x8*)&qs[(h * 128 + qt * 32 + ln31) * 36 + 16 + hi * 8];
      f32x16 s[4];
#pragma unroll
      for (int kt = 0; kt < 4; ++kt) {
        if (kt <= qt) {
          bf16x8 kf0 = *(const bf16x8*)&ksm[(h * 128 + kt * 32 + ln31) * 36 + hi * 8];
          bf16x8 kf1 = *(const bf16x8*)&ksm[(h * 128 + kt * 32 + ln31) * 36 + 16 + hi * 8];
          f32x16 z = {};
          z = __builtin_amdgcn_mfma_f32_32x32x16_bf16(kf0, qf0, z, 0, 0, 0);
          s[kt] = __builtin_amdgcn_mfma_f32_32x32x16_bf16(kf1, qf1, z, 0, 0, 0);
        }
      }
      // causal mask (diagonal tile only; garbage keys >=119 are key>query => masked)
#pragma unroll
      for (int rg = 0; rg < 16; ++rg) {
        const int c_lo = (rg & 3) + 8 * (rg >> 2);
        int crow = c_lo + 4 * hi;
        s[qt][rg] = (crow <= ln31) ? s[qt][rg] : NEGINF;
      }
      float mx = NEGINF;
#pragma unroll
      for (int kt = 0; kt < 4; ++kt)
        if (kt <= qt)
#pragma unroll
          for (int rg = 0; rg < 16; ++rg) mx = fmaxf(mx, s[kt][rg]);
      mx = fmaxf(mx, __shfl_xor(mx, 32));
      float sum = 0.0f;
#pragma unroll
      for (int kt = 0; kt < 4; ++kt)
        if (kt <= qt)
#pragma unroll
          for (int rg = 0; rg < 16; ++rg) {
            s[kt][rg] = __expf(s[kt][rg] - mx);
            sum += s[kt][rg];
          }
      sum += __shfl_xor(sum, 32);
      float inv = 1.0f / sum;
      unsigned pk[4][8];
#pragma unroll
      for (int kt = 0; kt < 4; ++kt) {
        if (kt <= qt) {
#pragma unroll
          for (int p = 0; p < 8; ++p) {
            union { bf16x2 v; unsigned u; } w;
            w.v[0] = (__bf16)(s[kt][2 * p] * inv);
            w.v[1] = (__bf16)(s[kt][2 * p + 1] * inv);
            pk[kt][p] = w.u;
          }
        }
      }
      f32x16 o = {};
#pragma unroll
      for (int kt = 0; kt < 4; ++kt) {
        if (kt <= qt) {
#pragma unroll
          for (int m = 0; m < 2; ++m) {
            unsigned f0 = (unsigned)__shfl_xor((int)pk[kt][4 * m + 0], 32);
            unsigned f1 = (unsigned)__shfl_xor((int)pk[kt][4 * m + 1], 32);
            unsigned f2 = (unsigned)__shfl_xor((int)pk[kt][4 * m + 2], 32);
            unsigned f3 = (unsigned)__shfl_xor((int)pk[kt][4 * m + 3], 32);
            union { unsigned w[4]; bf16x8 v; } Aw;
            Aw.w[0] = hi ? f2 : pk[kt][4 * m + 0];
            Aw.w[1] = hi ? f3 : pk[kt][4 * m + 1];
            Aw.w[2] = hi ? pk[kt][4 * m + 2] : f0;
            Aw.w[3] = hi ? pk[kt][4 * m + 3] : f1;
            bf16x8 vf = *(const bf16x8*)&vT[(h * 32 + ln31) * 128 +
                ((kt * 32 + m * 16 + hi * 8) ^ ((ln31 & 7) << 3))];
            o = __builtin_amdgcn_mfma_f32_32x32x16_bf16(Aw.v, vf, o, 0, 0, 0);
          }
        }
      }
      // y -> LDS (bf16, XOR-swizzled), merged layout col = h*32 + d
#pragma unroll
      for (int rg = 0; rg < 16; ++rg) {
        const int c_lo = (rg & 3) + 8 * (rg >> 2);
        int l = qt * 32 + c_lo + 4 * hi;
        if (l < L_SEQ) {
          int c = h * 32 + ln31;
          yL[l * 128 + (c ^ ((l & 7) << 3))] = (__bf16)o[rg];
        }
      }
    }
  }
  __syncthreads();

  // ======== FC2 + bias + SiLU: y from LDS, W frags from L2 (R9 form) ========
  {
    const int ln15 = lane & 15, kg = lane >> 4;
    int yr = wv * 16 + ln15;
    if (yr > L_SEQ - 1) yr = L_SEQ - 1;
    bf16x8 af2[4];
#pragma unroll
    for (int kb = 0; kb < 4; ++kb)
      af2[kb] = *(const bf16x8*)&yL[yr * 128 + ((kb * 32 + kg * 8) ^ ((yr & 7) << 3))];
    float bc[8];
#pragma unroll
    for (int nt = 0; nt < 8; ++nt) bc[nt] = bfc2[nt * 16 + ln15];
    f32x4 acc2[8] = {};
#pragma unroll
    for (int nt = 0; nt < 8; ++nt)
#pragma unroll
      for (int kb = 0; kb < 4; ++kb)
        acc2[nt] = __builtin_amdgcn_mfma_f32_16x16x32_bf16(
            af2[kb], *(const bf16x8*)&Wf2b[(((nt * 4 + kb) * 64) + lane) * 8],
            acc2[nt], 0, 0, 0);
#pragma unroll
    for (int nt = 0; nt < 8; ++nt)
#pragma unroll
      for (int r = 0; r < 4; ++r) {
        int row = wv * 16 + kg * 4 + r, c = nt * 16 + ln15;
        if (row < L_SEQ) {
          float vv = acc2[nt][r] + bc[nt];
          out[((size_t)b * L_SEQ + row) * 128 + c] = vv / (1.0f + __expf(-vv));
        }
      }
  }
}

extern "C" void kernel_launch(void* const* d_in, const int* in_sizes, int n_in,
                              void* d_out, int out_size, void* d_ws,
                              size_t ws_size, hipStream_t stream) {
  const float* x = (const float*)d_in[0];
  const float* Wqkv = (const float*)d_in[1];
  const float* bqkv = (const float*)d_in[2];
  const float* Wfc2 = (const float*)d_in[3];
  const float* bfc2 = (const float*)d_in[4];
  float* out = (float*)d_out;

  char* ws = (char*)d_ws;
  unsigned* tabu = (unsigned*)ws;                        // 30,464 B (pad 30,720)
  __bf16* Wb = (__bf16*)(ws + 30720);                    // 98,304 B
  float* bb2 = (float*)(ws + 30720 + 98304);             //  1,536 B
  __bf16* Wf2b = (__bf16*)(ws + 30720 + 98304 + 1536);   // 32,768 B (end 163,328)

  const int B = in_sizes[0] / (L_SEQ * D_MODEL);  // 2048
  rope_tab_kernel<<<(L_SEQ * 64 + 255) / 256, 256, 0, stream>>>(tabu);
  wprep_kernel<<<192, 256, 0, stream>>>(Wqkv, bqkv, Wb, bb2);
  wprep2_kernel<<<64, 256, 0, stream>>>(Wfc2, Wf2b);
  fused_all<<<B, 512, 0, stream>>>(x, Wb, bb2, tabu, Wf2b, bfc2, out);
}

// Round 13
// 369.769 us; speedup vs baseline: 1.0956x; 1.0001x over previous
//
#include <hip/hip_runtime.h>
#include <hip/hip_bf16.h>
#include <math.h>

// Fused QKV(+bias) -> RoPE -> 4-head causal attention -> FC2(+bias) -> SiLU
// B=2048, L=119, D=128, H=4, HD=32. fp32 in/out, bf16 MFMA internally.
// Head split: model channel c = d*4 + h. Head merge: out channel c' = h*32 + d.
//
// Round 11: R9 base (best verified: 221.8us) + three clean cuts.
//  - y kept in LDS (bf16, XOR-swizzled both sides) instead of out->L2->back:
//    FC2 reads ds_read_b128; out written exactly once (WRITE=output only).
//    tabL dropped (tab read from L2, as R8 -- identical perf) to fund yL.
//  - qs/ks stride 40 -> 36 (18 words/row, 16 distinct bank slots; R10-verified
//    conflict cut 2.9M->1.7M).
//  - ALL large arrays phase-scoped (R10 lesson: af[8] hoisted across attention
//    -> 627MB scratch traffic; R9 discipline restored).
// Layouts (m74/m101): 32x32 C/D: col=lane&31, row=(reg&3)+8*(reg>>2)+4*(lane>>5).
// A: row=lane&31, k=(lane>>5)*8+j. B: col=lane&31, same k.
// LDS: qs/ksm [4][128][36] 2x36,864 + vT [4][32][128] 32,768 + yL [128][128]
// 32,768 = 139,264 B.

#define L_SEQ 119
#define D_MODEL 128
#define SCALE 0.17677669529663687f  // 1/sqrt(32)
#define NEGINF -1e30f

typedef __bf16 bf16x8 __attribute__((ext_vector_type(8)));
typedef __bf16 bf16x2 __attribute__((ext_vector_type(2)));
typedef float f32x4 __attribute__((ext_vector_type(4)));
typedef float f32x16 __attribute__((ext_vector_type(16)));

__global__ void rope_tab_kernel(unsigned* __restrict__ tabu) {
  int i = blockIdx.x * blockDim.x + threadIdx.x;
  if (i >= L_SEQ * 64) return;
  int l = i >> 6, j = i & 63;
  float inv = 1.0f / powf(10000.0f, (float)(2 * j) / 128.0f);
  float f = (float)l * inv;
  union { bf16x2 v; unsigned u; } cs;
  cs.v[0] = (__bf16)cosf(f);
  cs.v[1] = (__bf16)sinf(f);
  tabu[i] = cs.u;
}

// Wb: A-operand frags for QKV (A=W). flat = ((nt*8 + ks)*64 + lane)*8 + j
//   row chan d = lane&31 (tile nt = h*3+qkv), k = ks*16 + (lane>>5)*8 + j
//   source: Wqkv[(qkv*128 + d*4 + h)*128 + k]
__global__ void wprep_kernel(const float* __restrict__ Wqkv,
                             const float* __restrict__ bqkv,
                             __bf16* __restrict__ Wb, float* __restrict__ bb2) {
  int i = blockIdx.x * 256 + threadIdx.x;  // 0..49151
  int j = i & 7, lane = (i >> 3) & 63, ks = (i >> 9) & 7, nt = i >> 12;
  int d = lane & 31;
  int h = nt / 3, qkv = nt % 3;
  int k = ks * 16 + (lane >> 5) * 8 + j;
  Wb[i] = (__bf16)Wqkv[(qkv * 128 + d * 4 + h) * 128 + k];
  if (i < 384) {
    int nt2 = i >> 5, dd = i & 31;
    bb2[i] = bqkv[(nt2 % 3) * 128 + dd * 4 + (nt2 / 3)];
  }
}

// Wfc2 B-frags (16x16x32 path): flat = ((nt*4 + kb)*64 + lane)*8 + j
__global__ void wprep2_kernel(const float* __restrict__ Wfc2,
                              __bf16* __restrict__ Wf2b) {
  int i = blockIdx.x * 256 + threadIdx.x;  // 0..16383
  int j = i & 7, lane = (i >> 3) & 63, kb = (i >> 9) & 3, nt = i >> 11;
  int n = nt * 16 + (lane & 15);
  int k = kb * 32 + (lane >> 4) * 8 + j;
  Wf2b[i] = (__bf16)Wfc2[n * 128 + k];
}

__global__ __launch_bounds__(512) void fused_all(
    const float* __restrict__ x, const __bf16* __restrict__ Wb,
    const float* __restrict__ bb2, const unsigned* __restrict__ tabu,
    const __bf16* __restrict__ Wf2b, const float* __restrict__ bfc2,
    float* __restrict__ out) {
  __shared__ __align__(16) __bf16 qs[4 * 128 * 36];   // 36,864 B
  __shared__ __align__(16) __bf16 ksm[4 * 128 * 36];  // 36,864 B
  __shared__ __align__(16) __bf16 vT[4 * 32 * 128];   // 32,768 B (XOR-swz)
  __shared__ __align__(16) __bf16 yL[128 * 128];      // 32,768 B (XOR-swz)

  const int t = threadIdx.x, b = blockIdx.x;
  const int lane = t & 63, wv = t >> 6;
  const int ln31 = lane & 31, hi = lane >> 5;

  // ---- zero vT tail cols 119..127
  for (int i = t; i < 4 * 32 * 9; i += 512) {
    int hd = i / 9, cc = L_SEQ + i % 9, d = hd & 31;
    vT[hd * 128 + (cc ^ ((d & 7) << 3))] = (__bf16)0.0f;
  }

  // ======== QKV: wave -> Mtile (wv&3), Ntile-group (wv>>2)*6 .. +5 ========
  const int mt = wv & 3, g2 = wv >> 2;
  const int l_me = mt * 32 + ln31;  // this lane's sequence row (col of C)
  const bool live = (l_me < L_SEQ);
  {
    int xr = live ? l_me : (L_SEQ - 1);
    const float* xrow = x + ((size_t)b * L_SEQ + xr) * 128;
    bf16x8 af[8];
#pragma unroll
    for (int ks = 0; ks < 8; ++ks) {
      float4 lo = *(const float4*)&xrow[ks * 16 + hi * 8];
      float4 hi4 = *(const float4*)&xrow[ks * 16 + hi * 8 + 4];
      bf16x8 v;
      v[0] = (__bf16)lo.x; v[1] = (__bf16)lo.y; v[2] = (__bf16)lo.z; v[3] = (__bf16)lo.w;
      v[4] = (__bf16)hi4.x; v[5] = (__bf16)hi4.y; v[6] = (__bf16)hi4.z; v[7] = (__bf16)hi4.w;
      af[ks] = v;
    }
#pragma unroll
    for (int r = 0; r < 3; ++r) {
      const int nt0 = g2 * 6 + 2 * r, nt1 = nt0 + 1;
      f32x16 a0 = {}, a1 = {};
#pragma unroll
      for (int ks = 0; ks < 8; ++ks) {
        bf16x8 wf0 = *(const bf16x8*)&Wb[(((nt0 * 8 + ks) * 64) + lane) * 8];
        bf16x8 wf1 = *(const bf16x8*)&Wb[(((nt1 * 8 + ks) * 64) + lane) * 8];
        a0 = __builtin_amdgcn_mfma_f32_32x32x16_bf16(wf0, af[ks], a0, 0, 0, 0);
        a1 = __builtin_amdgcn_mfma_f32_32x32x16_bf16(wf1, af[ks], a1, 0, 0, 0);
      }
      // epilogues
#pragma unroll
      for (int e = 0; e < 2; ++e) {
        const int nt = e ? nt1 : nt0;
        const f32x16& A = e ? a1 : a0;
        const int h = nt / 3, qkv = nt % 3;
        if (qkv < 2) {  // q or k: RoPE in-lane on reg pairs (rg, rg+8)
          __bf16* base = (qkv == 0) ? qs : ksm;
          if (live) {
#pragma unroll
            for (int rg = 0; rg < 8; ++rg) {
              const int c_lo = (rg & 3) + 8 * (rg >> 2);
              int d = c_lo + 4 * hi;  // 0..15
              union { bf16x2 v; unsigned u; } cs;
              cs.u = tabu[l_me * 64 + 4 * d + h];
              float c = (float)cs.v[0], s = (float)cs.v[1];
              float v1 = A[rg] + bb2[nt * 32 + d];
              float v2 = A[rg + 8] + bb2[nt * 32 + d + 16];
              if (qkv == 0) { v1 *= SCALE; v2 *= SCALE; }
              union { bf16x2 v; unsigned u; } pk;
              pk.v[0] = (__bf16)(v1 * c + v2 * s);
              pk.v[1] = (__bf16)(v2 * c - v1 * s);
              *(unsigned*)&base[(h * 128 + l_me) * 36 + 2 * d] = pk.u;
            }
          }
        } else {  // v: write vT[h][d][l] XOR-swizzled
          if (live) {
#pragma unroll
            for (int rg = 0; rg < 16; ++rg) {
              const int d = (rg & 3) + 8 * (rg >> 2) + 4 * hi;  // 0..31
              float val = A[rg] + bb2[nt * 32 + d];
              vT[(h * 32 + d) * 128 + (l_me ^ ((d & 7) << 3))] = (__bf16)val;
            }
          }
        }
      }
    }
  }
  __syncthreads();

  // ======== attention: wave -> head (wv>>1); tasks qt = {wv&1, 3-(wv&1)} ====
  {
    const int h = wv >> 1;
#pragma unroll
    for (int ts = 0; ts < 2; ++ts) {
      const int qt = ts ? (3 - (wv & 1)) : (wv & 1);
      bf16x8 qf0 = *(const bf16x8*)&qs[(h * 128 + qt * 32 + ln31) * 36 + hi * 8];
      bf16x8 qf1 = *(const bf16x8*)&qs[(h * 128 + qt * 32 + ln31) * 36 + 16 + hi * 8];
      f32x16 s[4];
#pragma unroll
      for (int kt = 0; kt < 4; ++kt) {
        if (kt <= qt) {
          bf16x8 kf0 = *(const bf16x8*)&ksm[(h * 128 + kt * 32 + ln31) * 36 + hi * 8];
          bf16x8 kf1 = *(const bf16x8*)&ksm[(h * 128 + kt * 32 + ln31) * 36 + 16 + hi * 8];
          f32x16 z = {};
          z = __builtin_amdgcn_mfma_f32_32x32x16_bf16(kf0, qf0, z, 0, 0, 0);
          s[kt] = __builtin_amdgcn_mfma_f32_32x32x16_bf16(kf1, qf1, z, 0, 0, 0);
        }
      }
      // causal mask (diagonal tile only; garbage keys >=119 are key>query => masked)
#pragma unroll
      for (int rg = 0; rg < 16; ++rg) {
        const int c_lo = (rg & 3) + 8 * (rg >> 2);
        int crow = c_lo + 4 * hi;
        s[qt][rg] = (crow <= ln31) ? s[qt][rg] : NEGINF;
      }
      float mx = NEGINF;
#pragma unroll
      for (int kt = 0; kt < 4; ++kt)
        if (kt <= qt)
#pragma unroll
          for (int rg = 0; rg < 16; ++rg) mx = fmaxf(mx, s[kt][rg]);
      mx = fmaxf(mx, __shfl_xor(mx, 32));
      float sum = 0.0f;
#pragma unroll
      for (int kt = 0; kt < 4; ++kt)
        if (kt <= qt)
#pragma unroll
          for (int rg = 0; rg < 16; ++rg) {
            s[kt][rg] = __expf(s[kt][rg] - mx);
            sum += s[kt][rg];
          }
      sum += __shfl_xor(sum, 32);
      float inv = 1.0f / sum;
      unsigned pk[4][8];
#pragma unroll
      for (int kt = 0; kt < 4; ++kt) {
        if (kt <= qt) {
#pragma unroll
          for (int p = 0; p < 8; ++p) {
            union { bf16x2 v; unsigned u; } w;
            w.v[0] = (__bf16)(s[kt][2 * p] * inv);
            w.v[1] = (__bf16)(s[kt][2 * p + 1] * inv);
            pk[kt][p] = w.u;
          }
        }
      }
      f32x16 o = {};
#pragma unroll
      for (int kt = 0; kt < 4; ++kt) {
        if (kt <= qt) {
#pragma unroll
          for (int m = 0; m < 2; ++m) {
            unsigned f0 = (unsigned)__shfl_xor((int)pk[kt][4 * m + 0], 32);
            unsigned f1 = (unsigned)__shfl_xor((int)pk[kt][4 * m + 1], 32);
            unsigned f2 = (unsigned)__shfl_xor((int)pk[kt][4 * m + 2], 32);
            unsigned f3 = (unsigned)__shfl_xor((int)pk[kt][4 * m + 3], 32);
            union { unsigned w[4]; bf16x8 v; } Aw;
            Aw.w[0] = hi ? f2 : pk[kt][4 * m + 0];
            Aw.w[1] = hi ? f3 : pk[kt][4 * m + 1];
            Aw.w[2] = hi ? pk[kt][4 * m + 2] : f0;
            Aw.w[3] = hi ? pk[kt][4 * m + 3] : f1;
            bf16x8 vf = *(const bf16x8*)&vT[(h * 32 + ln31) * 128 +
                ((kt * 32 + m * 16 + hi * 8) ^ ((ln31 & 7) << 3))];
            o = __builtin_amdgcn_mfma_f32_32x32x16_bf16(Aw.v, vf, o, 0, 0, 0);
          }
        }
      }
      // y -> LDS (bf16, XOR-swizzled), merged layout col = h*32 + d
#pragma unroll
      for (int rg = 0; rg < 16; ++rg) {
        const int c_lo = (rg & 3) + 8 * (rg >> 2);
        int l = qt * 32 + c_lo + 4 * hi;
        if (l < L_SEQ) {
          int c = h * 32 + ln31;
          yL[l * 128 + (c ^ ((l & 7) << 3))] = (__bf16)o[rg];
        }
      }
    }
  }
  __syncthreads();

  // ======== FC2 + bias + SiLU: y from LDS, W frags from L2 (R9 form) ========
  {
    const int ln15 = lane & 15, kg = lane >> 4;
    int yr = wv * 16 + ln15;
    if (yr > L_SEQ - 1) yr = L_SEQ - 1;
    bf16x8 af2[4];
#pragma unroll
    for (int kb = 0; kb < 4; ++kb)
      af2[kb] = *(const bf16x8*)&yL[yr * 128 + ((kb * 32 + kg * 8) ^ ((yr & 7) << 3))];
    float bc[8];
#pragma unroll
    for (int nt = 0; nt < 8; ++nt) bc[nt] = bfc2[nt * 16 + ln15];
    f32x4 acc2[8] = {};
#pragma unroll
    for (int nt = 0; nt < 8; ++nt)
#pragma unroll
      for (int kb = 0; kb < 4; ++kb)
        acc2[nt] = __builtin_amdgcn_mfma_f32_16x16x32_bf16(
            af2[kb], *(const bf16x8*)&Wf2b[(((nt * 4 + kb) * 64) + lane) * 8],
            acc2[nt], 0, 0, 0);
#pragma unroll
    for (int nt = 0; nt < 8; ++nt)
#pragma unroll
      for (int r = 0; r < 4; ++r) {
        int row = wv * 16 + kg * 4 + r, c = nt * 16 + ln15;
        if (row < L_SEQ) {
          float vv = acc2[nt][r] + bc[nt];
          out[((size_t)b * L_SEQ + row) * 128 + c] = vv / (1.0f + __expf(-vv));
        }
      }
  }
}

extern "C" void kernel_launch(void* const* d_in, const int* in_sizes, int n_in,
                              void* d_out, int out_size, void* d_ws,
                              size_t ws_size, hipStream_t stream) {
  const float* x = (const float*)d_in[0];
  const float* Wqkv = (const float*)d_in[1];
  const float* bqkv = (const float*)d_in[2];
  const float* Wfc2 = (const float*)d_in[3];
  const float* bfc2 = (const float*)d_in[4];
  float* out = (float*)d_out;

  char* ws = (char*)d_ws;
  unsigned* tabu = (unsigned*)ws;                        // 30,464 B (pad 30,720)
  __bf16* Wb = (__bf16*)(ws + 30720);                    // 98,304 B
  float* bb2 = (float*)(ws + 30720 + 98304);             //  1,536 B
  __bf16* Wf2b = (__bf16*)(ws + 30720 + 98304 + 1536);   // 32,768 B (end 163,328)

  const int B = in_sizes[0] / (L_SEQ * D_MODEL);  // 2048
  rope_tab_kernel<<<(L_SEQ * 64 + 255) / 256, 256, 0, stream>>>(tabu);
  wprep_kernel<<<192, 256, 0, stream>>>(Wqkv, bqkv, Wb, bb2);
  wprep2_kernel<<<64, 256, 0, stream>>>(Wfc2, Wf2b);
  fused_all<<<B, 512, 0, stream>>>(x, Wb, bb2, tabu, Wf2b, bfc2, out);
}

// Round 14
// 251.357 us; speedup vs baseline: 1.6118x; 1.4711x over previous
//
#include <hip/hip_runtime.h>
#include <hip/hip_bf16.h>
#include <math.h>

// Fused QKV(+bias) -> RoPE -> 4-head causal attention -> FC2(+bias) -> SiLU
// B=2048, L=119, D=128, H=4, HD=32. fp32 in/out, bf16 MFMA internally.
// Head split: model channel c = d*4 + h. Head merge: out channel c' = h*32 + d.
//
// Round 13: CODE-SIZE A/B on the R9 base (221.8us verified). Hypothesis: dur
// invariance across occupancy/LDS/conflicts (R5-R9, ~205us) + per-wave issue
// ~15% + MfmaUtil 7.5% = instruction-fetch bound (fully-unrolled ~30-40KB
// bodies). Diffs from R9 (all reduce register pressure; R10/R11 lesson --
// never extend live ranges across phases):
//  1. QKV rolled to 3 iters (paired a0/a1 body, runtime wave-uniform epilogue).
//  2. Attention ts-loop rolled (runtime qt; diag mask inside UNROLLED kt loop
//     so s[] indices stay compile-time -- rule #20).
//  3. FC2 nt-loop rolled (single f32x4 acc).
//  4. qs/ks stride 40->36 (validated conflict cut 2.9M->1M, R10/R11).
// Layouts (m74/m101): 32x32 C/D col=lane&31, row=(reg&3)+8*(reg>>2)+4*(lane>>5).
// A: row=lane&31, k=(lane>>5)*8+j. B: col=lane&31, same k.
// LDS: qs/ksm 2x36,864 + vT 32,768 + tabL 30,940 = 137,436 B.

#define L_SEQ 119
#define D_MODEL 128
#define SCALE 0.17677669529663687f  // 1/sqrt(32)
#define NEGINF -1e30f

typedef __bf16 bf16x8 __attribute__((ext_vector_type(8)));
typedef __bf16 bf16x2 __attribute__((ext_vector_type(2)));
typedef float f32x4 __attribute__((ext_vector_type(4)));
typedef float f32x16 __attribute__((ext_vector_type(16)));

__global__ void rope_tab_kernel(unsigned* __restrict__ tabu) {
  int i = blockIdx.x * blockDim.x + threadIdx.x;
  if (i >= L_SEQ * 64) return;
  int l = i >> 6, j = i & 63;
  float inv = 1.0f / powf(10000.0f, (float)(2 * j) / 128.0f);
  float f = (float)l * inv;
  union { bf16x2 v; unsigned u; } cs;
  cs.v[0] = (__bf16)cosf(f);
  cs.v[1] = (__bf16)sinf(f);
  tabu[i] = cs.u;
}

// Wb: A-operand frags for QKV (A=W). flat = ((nt*8 + ks)*64 + lane)*8 + j
//   row chan d = lane&31 (tile nt = h*3+qkv), k = ks*16 + (lane>>5)*8 + j
__global__ void wprep_kernel(const float* __restrict__ Wqkv,
                             const float* __restrict__ bqkv,
                             __bf16* __restrict__ Wb, float* __restrict__ bb2) {
  int i = blockIdx.x * 256 + threadIdx.x;  // 0..49151
  int j = i & 7, lane = (i >> 3) & 63, ks = (i >> 9) & 7, nt = i >> 12;
  int d = lane & 31;
  int h = nt / 3, qkv = nt % 3;
  int k = ks * 16 + (lane >> 5) * 8 + j;
  Wb[i] = (__bf16)Wqkv[(qkv * 128 + d * 4 + h) * 128 + k];
  if (i < 384) {
    int nt2 = i >> 5, dd = i & 31;
    bb2[i] = bqkv[(nt2 % 3) * 128 + dd * 4 + (nt2 / 3)];
  }
}

// Wfc2 B-frags (16x16x32 path): flat = ((nt*4 + kb)*64 + lane)*8 + j
__global__ void wprep2_kernel(const float* __restrict__ Wfc2,
                              __bf16* __restrict__ Wf2b) {
  int i = blockIdx.x * 256 + threadIdx.x;  // 0..16383
  int j = i & 7, lane = (i >> 3) & 63, kb = (i >> 9) & 3, nt = i >> 11;
  int n = nt * 16 + (lane & 15);
  int k = kb * 32 + (lane >> 4) * 8 + j;
  Wf2b[i] = (__bf16)Wfc2[n * 128 + k];
}

__global__ __launch_bounds__(512) void fused_all(
    const float* __restrict__ x, const __bf16* __restrict__ Wb,
    const float* __restrict__ bb2, const unsigned* __restrict__ tabu,
    const __bf16* __restrict__ Wf2b, const float* __restrict__ bfc2,
    float* __restrict__ out) {
  __shared__ __align__(16) __bf16 qs[4 * 128 * 36];   // 36,864 B
  __shared__ __align__(16) __bf16 ksm[4 * 128 * 36];  // 36,864 B
  __shared__ __align__(16) __bf16 vT[4 * 32 * 128];   // 32,768 B (XOR-swz)
  __shared__ unsigned tabL[L_SEQ * 65];               // 30,940 B

  const int t = threadIdx.x, b = blockIdx.x;
  const int lane = t & 63, wv = t >> 6;
  const int ln31 = lane & 31, hi = lane >> 5;

  // ---- stage RoPE table (stride 65 words -> conflict-free lane-l reads)
  for (int i = t; i < L_SEQ * 64; i += 512)
    tabL[(i >> 6) * 65 + (i & 63)] = tabu[i];
  // ---- zero vT tail cols 119..127
  for (int i = t; i < 4 * 32 * 9; i += 512) {
    int hd = i / 9, cc = L_SEQ + i % 9, d = hd & 31;
    vT[hd * 128 + (cc ^ ((d & 7) << 3))] = (__bf16)0.0f;
  }
  __syncthreads();

  // ======== QKV: wave -> Mtile (wv&3), Ntile-group (wv>>2)*6 .. +5 ========
  const int mt = wv & 3, g2 = wv >> 2;
  const int l_me = mt * 32 + ln31;  // this lane's sequence row (col of C)
  const bool live = (l_me < L_SEQ);
  {
    int xr = live ? l_me : (L_SEQ - 1);
    const float* xrow = x + ((size_t)b * L_SEQ + xr) * 128;
    bf16x8 af[8];
#pragma unroll
    for (int ks = 0; ks < 8; ++ks) {
      float4 lo = *(const float4*)&xrow[ks * 16 + hi * 8];
      float4 hi4 = *(const float4*)&xrow[ks * 16 + hi * 8 + 4];
      bf16x8 v;
      v[0] = (__bf16)lo.x; v[1] = (__bf16)lo.y; v[2] = (__bf16)lo.z; v[3] = (__bf16)lo.w;
      v[4] = (__bf16)hi4.x; v[5] = (__bf16)hi4.y; v[6] = (__bf16)hi4.z; v[7] = (__bf16)hi4.w;
      af[ks] = v;
    }
#pragma unroll 1
    for (int rr = 0; rr < 3; ++rr) {  // ROLLED: 1/3 the QKV code
      const int nt0 = g2 * 6 + 2 * rr, nt1 = nt0 + 1;
      f32x16 a0 = {}, a1 = {};
#pragma unroll
      for (int ks = 0; ks < 8; ++ks) {
        bf16x8 wf0 = *(const bf16x8*)&Wb[(((nt0 * 8 + ks) * 64) + lane) * 8];
        bf16x8 wf1 = *(const bf16x8*)&Wb[(((nt1 * 8 + ks) * 64) + lane) * 8];
        a0 = __builtin_amdgcn_mfma_f32_32x32x16_bf16(wf0, af[ks], a0, 0, 0, 0);
        a1 = __builtin_amdgcn_mfma_f32_32x32x16_bf16(wf1, af[ks], a1, 0, 0, 0);
      }
#pragma unroll
      for (int e = 0; e < 2; ++e) {
        const int nt = e ? nt1 : nt0;          // runtime wave-uniform
        const f32x16& A = e ? a1 : a0;         // compile-time select
        const int h = nt / 3, qkv = nt - h * 3;
        if (live) {
          if (qkv == 2) {  // v -> vT XOR-swizzled
#pragma unroll
            for (int rg = 0; rg < 16; ++rg) {
              const int d = (rg & 3) + 8 * (rg >> 2) + 4 * hi;  // 0..31
              float val = A[rg] + bb2[nt * 32 + d];
              vT[(h * 32 + d) * 128 + (l_me ^ ((d & 7) << 3))] = (__bf16)val;
            }
          } else {  // q or k: in-lane RoPE on reg pairs (rg, rg+8)
            __bf16* base = qkv ? ksm : qs;
#pragma unroll
            for (int rg = 0; rg < 8; ++rg) {
              const int c_lo = (rg & 3) + 8 * (rg >> 2);
              int d = c_lo + 4 * hi;  // 0..15
              union { bf16x2 v; unsigned u; } cs;
              cs.u = tabL[l_me * 65 + 4 * d + h];
              float c = (float)cs.v[0], s = (float)cs.v[1];
              float v1 = A[rg] + bb2[nt * 32 + d];
              float v2 = A[rg + 8] + bb2[nt * 32 + d + 16];
              if (qkv == 0) { v1 *= SCALE; v2 *= SCALE; }
              union { bf16x2 v; unsigned u; } pk;
              pk.v[0] = (__bf16)(v1 * c + v2 * s);
              pk.v[1] = (__bf16)(v2 * c - v1 * s);
              *(unsigned*)&base[(h * 128 + l_me) * 36 + 2 * d] = pk.u;
            }
          }
        }
      }
    }
  }
  __syncthreads();

  // ======== attention: wave -> head (wv>>1); ROLLED ts loop ========
  {
    const int h = wv >> 1;
#pragma unroll 1
    for (int ts = 0; ts < 2; ++ts) {  // 1/2 the attention code
      const int qt = ts ? (3 - (wv & 1)) : (wv & 1);  // runtime wave-uniform
      bf16x8 qf0 = *(const bf16x8*)&qs[(h * 128 + qt * 32 + ln31) * 36 + hi * 8];
      bf16x8 qf1 = *(const bf16x8*)&qs[(h * 128 + qt * 32 + ln31) * 36 + 16 + hi * 8];
      f32x16 s[4];
#pragma unroll
      for (int kt = 0; kt < 4; ++kt) {
        if (kt <= qt) {
          bf16x8 kf0 = *(const bf16x8*)&ksm[(h * 128 + kt * 32 + ln31) * 36 + hi * 8];
          bf16x8 kf1 = *(const bf16x8*)&ksm[(h * 128 + kt * 32 + ln31) * 36 + 16 + hi * 8];
          f32x16 z = {};
          z = __builtin_amdgcn_mfma_f32_32x32x16_bf16(kf0, qf0, z, 0, 0, 0);
          s[kt] = __builtin_amdgcn_mfma_f32_32x32x16_bf16(kf1, qf1, z, 0, 0, 0);
          if (kt == qt) {  // diagonal mask, s[] index compile-time (rule #20)
#pragma unroll
            for (int rg = 0; rg < 16; ++rg) {
              const int c_lo = (rg & 3) + 8 * (rg >> 2);
              int crow = c_lo + 4 * hi;
              s[kt][rg] = (crow <= ln31) ? s[kt][rg] : NEGINF;
            }
          }
        }
      }
      float mx = NEGINF;
#pragma unroll
      for (int kt = 0; kt < 4; ++kt)
        if (kt <= qt)
#pragma unroll
          for (int rg = 0; rg < 16; ++rg) mx = fmaxf(mx, s[kt][rg]);
      mx = fmaxf(mx, __shfl_xor(mx, 32));
      float sum = 0.0f;
#pragma unroll
      for (int kt = 0; kt < 4; ++kt)
        if (kt <= qt)
#pragma unroll
          for (int rg = 0; rg < 16; ++rg) {
            s[kt][rg] = __expf(s[kt][rg] - mx);
            sum += s[kt][rg];
          }
      sum += __shfl_xor(sum, 32);
      float inv = 1.0f / sum;
      unsigned pk[4][8];
#pragma unroll
      for (int kt = 0; kt < 4; ++kt) {
        if (kt <= qt) {
#pragma unroll
          for (int p = 0; p < 8; ++p) {
            union { bf16x2 v; unsigned u; } w;
            w.v[0] = (__bf16)(s[kt][2 * p] * inv);
            w.v[1] = (__bf16)(s[kt][2 * p + 1] * inv);
            pk[kt][p] = w.u;
          }
        }
      }
      f32x16 o = {};
#pragma unroll
      for (int kt = 0; kt < 4; ++kt) {
        if (kt <= qt) {
#pragma unroll
          for (int m = 0; m < 2; ++m) {
            unsigned f0 = (unsigned)__shfl_xor((int)pk[kt][4 * m + 0], 32);
            unsigned f1 = (unsigned)__shfl_xor((int)pk[kt][4 * m + 1], 32);
            unsigned f2 = (unsigned)__shfl_xor((int)pk[kt][4 * m + 2], 32);
            unsigned f3 = (unsigned)__shfl_xor((int)pk[kt][4 * m + 3], 32);
            union { unsigned w[4]; bf16x8 v; } Aw;
            Aw.w[0] = hi ? f2 : pk[kt][4 * m + 0];
            Aw.w[1] = hi ? f3 : pk[kt][4 * m + 1];
            Aw.w[2] = hi ? pk[kt][4 * m + 2] : f0;
            Aw.w[3] = hi ? pk[kt][4 * m + 3] : f1;
            bf16x8 vf = *(const bf16x8*)&vT[(h * 32 + ln31) * 128 +
                ((kt * 32 + m * 16 + hi * 8) ^ ((ln31 & 7) << 3))];
            o = __builtin_amdgcn_mfma_f32_32x32x16_bf16(Aw.v, vf, o, 0, 0, 0);
          }
        }
      }
#pragma unroll
      for (int rg = 0; rg < 16; ++rg) {
        const int c_lo = (rg & 3) + 8 * (rg >> 2);
        int l = qt * 32 + c_lo + 4 * hi;
        if (l < L_SEQ)
          out[((size_t)b * L_SEQ + l) * 128 + h * 32 + ln31] = o[rg];
      }
    }
  }
  __syncthreads();

  // ======== FC2 + bias + SiLU: ROLLED nt loop (1/8 the code) ========
  {
    const int ln15 = lane & 15, kg = lane >> 4;
    int yr = wv * 16 + ln15;
    if (yr > L_SEQ - 1) yr = L_SEQ - 1;
    const float* yrow = out + ((size_t)b * L_SEQ + yr) * 128;
    bf16x8 af2[4];
#pragma unroll
    for (int kb = 0; kb < 4; ++kb) {
      float4 lo = *(const float4*)&yrow[kb * 32 + kg * 8];
      float4 hi4 = *(const float4*)&yrow[kb * 32 + kg * 8 + 4];
      bf16x8 v;
      v[0] = (__bf16)lo.x; v[1] = (__bf16)lo.y; v[2] = (__bf16)lo.z; v[3] = (__bf16)lo.w;
      v[4] = (__bf16)hi4.x; v[5] = (__bf16)hi4.y; v[6] = (__bf16)hi4.z; v[7] = (__bf16)hi4.w;
      af2[kb] = v;
    }
#pragma unroll 1
    for (int nt = 0; nt < 8; ++nt) {
      f32x4 a2 = {};
#pragma unroll
      for (int kb = 0; kb < 4; ++kb)
        a2 = __builtin_amdgcn_mfma_f32_16x16x32_bf16(
            af2[kb], *(const bf16x8*)&Wf2b[(((nt * 4 + kb) * 64) + lane) * 8],
            a2, 0, 0, 0);
      float bc = bfc2[nt * 16 + ln15];
#pragma unroll
      for (int r = 0; r < 4; ++r) {
        int row = wv * 16 + kg * 4 + r, c = nt * 16 + ln15;
        if (row < L_SEQ) {
          float vv = a2[r] + bc;
          out[((size_t)b * L_SEQ + row) * 128 + c] = vv / (1.0f + __expf(-vv));
        }
      }
    }
  }
}

extern "C" void kernel_launch(void* const* d_in, const int* in_sizes, int n_in,
                              void* d_out, int out_size, void* d_ws,
                              size_t ws_size, hipStream_t stream) {
  const float* x = (const float*)d_in[0];
  const float* Wqkv = (const float*)d_in[1];
  const float* bqkv = (const float*)d_in[2];
  const float* Wfc2 = (const float*)d_in[3];
  const float* bfc2 = (const float*)d_in[4];
  float* out = (float*)d_out;

  char* ws = (char*)d_ws;
  unsigned* tabu = (unsigned*)ws;                        // 30,464 B (pad 30,720)
  __bf16* Wb = (__bf16*)(ws + 30720);                    // 98,304 B
  float* bb2 = (float*)(ws + 30720 + 98304);             //  1,536 B
  __bf16* Wf2b = (__bf16*)(ws + 30720 + 98304 + 1536);   // 32,768 B (end 163,328)

  const int B = in_sizes[0] / (L_SEQ * D_MODEL);  // 2048
  rope_tab_kernel<<<(L_SEQ * 64 + 255) / 256, 256, 0, stream>>>(tabu);
  wprep_kernel<<<192, 256, 0, stream>>>(Wqkv, bqkv, Wb, bb2);
  wprep2_kernel<<<64, 256, 0, stream>>>(Wfc2, Wf2b);
  fused_all<<<B, 512, 0, stream>>>(x, Wb, bb2, tabu, Wf2b, bfc2, out);
}